// Round 9
// baseline (206.267 us; speedup 1.0000x reference)
//
#include <hip/hip_runtime.h>
#include <hip/hip_bf16.h>
#include <math.h>

#define M_TOT 8192
#define D_DIM 1024
#define E_NUM 8
#define P_DIM 1024
#define K_TOT (E_NUM * D_DIM)  // 8192

typedef __attribute__((ext_vector_type(8))) short short8;
typedef __attribute__((ext_vector_type(4))) float f32x4;
typedef __attribute__((ext_vector_type(8))) unsigned short u16x8;

// round-to-nearest-even f32 -> bf16 (finite inputs)
static __device__ __forceinline__ unsigned short f2bf(float f) {
  unsigned u = __builtin_bit_cast(unsigned, f);
  unsigned r = (u + 0x7fffu + ((u >> 16) & 1u)) >> 16;
  return (unsigned short)r;
}

// ---------------- gate: softmax(x @ gate_w + gate_b) -> [M, E] fp32 ----------------
__global__ __launch_bounds__(256) void gate_kernel(const float* __restrict__ x,
                                                   const float* __restrict__ gw,
                                                   const float* __restrict__ gb,
                                                   float* __restrict__ gate) {
  const int row  = blockIdx.x * 4 + (threadIdx.x >> 6);
  const int lane = threadIdx.x & 63;
  const float* xr = x + (size_t)row * D_DIM;
  float acc[E_NUM];
#pragma unroll
  for (int e = 0; e < E_NUM; ++e) acc[e] = 0.f;
#pragma unroll
  for (int it = 0; it < 16; ++it) {
    const int d = it * 64 + lane;
    const float xv = xr[d];
    const float4* g4 = reinterpret_cast<const float4*>(gw + (size_t)d * E_NUM);
    float4 a = g4[0], b = g4[1];
    acc[0] += xv * a.x; acc[1] += xv * a.y; acc[2] += xv * a.z; acc[3] += xv * a.w;
    acc[4] += xv * b.x; acc[5] += xv * b.y; acc[6] += xv * b.z; acc[7] += xv * b.w;
  }
#pragma unroll
  for (int off = 32; off >= 1; off >>= 1) {
#pragma unroll
    for (int e = 0; e < E_NUM; ++e) acc[e] += __shfl_xor(acc[e], off, 64);
  }
  if (lane == 0) {
    float v[E_NUM], mx = -1e30f;
#pragma unroll
    for (int e = 0; e < E_NUM; ++e) { v[e] = acc[e] + gb[e]; mx = fmaxf(mx, v[e]); }
    float s = 0.f;
#pragma unroll
    for (int e = 0; e < E_NUM; ++e) { v[e] = expf(v[e] - mx); s += v[e]; }
    const float inv = 1.f / s;
#pragma unroll
    for (int e = 0; e < E_NUM; ++e) gate[(size_t)row * E_NUM + e] = v[e] * inv;
  }
}

// ---------------- W [E][D][P] f32 -> wt [P][E*D] bf16, swizzle baked per 64-short K-block ----------------
__global__ __launch_bounds__(256) void wtrans2_kernel(const float* __restrict__ w,
                                                      unsigned short* __restrict__ wt) {
  __shared__ float tile[64][65];
  const int e  = blockIdx.z;
  const int p0 = blockIdx.y * 64;
  const int d0 = blockIdx.x * 64;
  const int tx = threadIdx.x & 63;
  const int ty = threadIdx.x >> 6;
  const float* src = w + ((size_t)e * D_DIM + d0) * P_DIM + p0;
#pragma unroll
  for (int i = 0; i < 16; ++i) {
    const int dr = i * 4 + ty;
    tile[dr][tx] = src[(size_t)dr * P_DIM + tx];
  }
  __syncthreads();
#pragma unroll
  for (int i = 0; i < 16; ++i) {
    const int pr = i * 4 + ty;
    const int c = tx ^ ((pr & 7) << 3);  // involution, 16B-chunk granular
    wt[(size_t)(p0 + pr) * K_TOT + e * D_DIM + d0 + c] = f2bf(tile[tx][pr]);
  }
}

// ---------------- A'[m][e*1024+d] = bf16(gate[m,e]*x[m,d]), swizzle baked per 64-short K-block ----------------
__global__ __launch_bounds__(256) void aprep_kernel(const float* __restrict__ x,
                                                    const float* __restrict__ gate,
                                                    unsigned short* __restrict__ ap) {
  const int tid = threadIdx.x;
  const int m   = blockIdx.x * 2 + (tid >> 7);
  const int jd  = tid & 127;
  const float4* xp = reinterpret_cast<const float4*>(x + (size_t)m * D_DIM + jd * 8);
  const float4 p = xp[0], q = xp[1];
  unsigned short* row = ap + (size_t)m * K_TOT;
  const int cbase = (jd >> 3) * 8 + ((jd & 7) ^ (m & 7));
#pragma unroll
  for (int e = 0; e < E_NUM; ++e) {
    const float gs = gate[(size_t)m * E_NUM + e];
    u16x8 v;
    v[0] = f2bf(p.x * gs); v[1] = f2bf(p.y * gs);
    v[2] = f2bf(p.z * gs); v[3] = f2bf(p.w * gs);
    v[4] = f2bf(q.x * gs); v[5] = f2bf(q.y * gs);
    v[6] = f2bf(q.z * gs); v[7] = f2bf(q.w * gs);
    *reinterpret_cast<u16x8*>(&row[(size_t)(e * 128 + cbase) * 8]) = v;
  }
}

// ---- split-K=2 GEMM, round-8 structure, 36KB LDS, launch_bounds(256,4) -> 4 blocks/CU ----
__global__ __launch_bounds__(256, 4) void gemm_sk3_kernel(
    const unsigned short* __restrict__ ap,
    const unsigned short* __restrict__ wt,
    const float* __restrict__ gate,
    const float* __restrict__ eb,
    float* __restrict__ out) {
  __shared__ unsigned short lA[128 * 64];   // 16 KB
  __shared__ unsigned short lB[128 * 64];   // 16 KB
  __shared__ float lG[128 * 8];             // 4 KB  -> 36 KB total

  const int tid  = threadIdx.x;
  const int lane = tid & 63;
  const int wid  = tid >> 6;
  const int wr   = wid >> 1, wc = wid & 1;

  // 1024 blocks = 8 XCDs x (mtl8 x nt8 x kh2). All 16 blocks sharing an A'-panel
  // (same mt: 8 nt x 2 kh) sit on ONE XCD -> A panel L2-resident.
  const int bid = blockIdx.x;
  const int xcd = bid & 7, idx = bid >> 3;
  const int kh  = idx & 1;
  const int nt  = (idx >> 1) & 7;
  const int mt  = xcd * 8 + (idx >> 4);
  const int m0  = mt * 128, n0 = nt * 128;

  reinterpret_cast<float4*>(lG)[tid] =
      reinterpret_cast<const float4*>(gate + (size_t)m0 * E_NUM)[tid];

  f32x4 acc[4][4];
#pragma unroll
  for (int i = 0; i < 4; ++i)
#pragma unroll
    for (int j = 0; j < 4; ++j)
#pragma unroll
      for (int k = 0; k < 4; ++k) acc[i][j][k] = 0.f;

  const int r0 = tid >> 3;  // 0..31
  const int c8 = tid & 7;   // 16B chunk within 64-short block
  const unsigned short* pA = ap + (size_t)(m0 + r0) * K_TOT + (size_t)kh * 4096 + c8 * 8;
  const unsigned short* pB = wt + (size_t)(n0 + r0) * K_TOT + (size_t)kh * 4096 + c8 * 8;

  for (int kt = 0; kt < 64; ++kt) {
    __syncthreads();  // previous tile's LDS reads complete
#pragma unroll
    for (int i = 0; i < 4; ++i) {
      __builtin_amdgcn_global_load_lds(
          (const __attribute__((address_space(1))) void*)(pA + (size_t)i * 32 * K_TOT),
          (__attribute__((address_space(3))) void*)&lA[(tid + i * 256) * 8], 16, 0, 0);
    }
#pragma unroll
    for (int i = 0; i < 4; ++i) {
      __builtin_amdgcn_global_load_lds(
          (const __attribute__((address_space(1))) void*)(pB + (size_t)i * 32 * K_TOT),
          (__attribute__((address_space(3))) void*)&lB[(tid + i * 256) * 8], 16, 0, 0);
    }
    __syncthreads();  // compiler drains vmcnt before barrier
#pragma unroll
    for (int kk = 0; kk < 2; ++kk) {
      const int e0 = kk * 32 + (lane >> 4) * 8;
      short8 a[4], b[4];
#pragma unroll
      for (int m = 0; m < 4; ++m) {
        const int r = wr * 64 + m * 16 + (lane & 15);
        a[m] = *reinterpret_cast<const short8*>(&lA[r * 64 + (e0 ^ ((r & 7) << 3))]);
      }
#pragma unroll
      for (int n = 0; n < 4; ++n) {
        const int r = wc * 64 + n * 16 + (lane & 15);
        b[n] = *reinterpret_cast<const short8*>(&lB[r * 64 + (e0 ^ ((r & 7) << 3))]);
      }
#pragma unroll
      for (int m = 0; m < 4; ++m)
#pragma unroll
        for (int n = 0; n < 4; ++n)
          acc[m][n] = __builtin_amdgcn_mfma_f32_16x16x32_bf16(a[m], b[n], acc[m][n], 0, 0, 0);
    }
    pA += 64;
    pB += 64;
  }

  // ---- epilogue: atomic accumulate; kh==0 adds gate-weighted bias (eb direct from L2) ----
#pragma unroll
  for (int n = 0; n < 4; ++n) {
    const int cl = wc * 64 + n * 16 + (lane & 15);
    float lb[E_NUM];
    if (kh == 0) {
#pragma unroll
      for (int e = 0; e < E_NUM; ++e) lb[e] = eb[(size_t)e * P_DIM + n0 + cl];
    }
#pragma unroll
    for (int m = 0; m < 4; ++m) {
#pragma unroll
      for (int reg = 0; reg < 4; ++reg) {
        const int r = wr * 64 + m * 16 + (lane >> 4) * 4 + reg;
        float v = acc[m][n][reg];
        if (kh == 0) {
          float bsum = 0.f;
#pragma unroll
          for (int e = 0; e < E_NUM; ++e) bsum += lG[r * 8 + e] * lb[e];
          v += bsum;
        }
        atomicAdd(&out[(size_t)(m0 + r) * P_DIM + n0 + cl], v);
      }
    }
  }
}

// ============================ FALLBACK PATH (round-2, passing) ============================

__global__ __launch_bounds__(256) void wtrans_kernel(const float* __restrict__ w,
                                                     unsigned short* __restrict__ wt) {
  __shared__ float tile[64][65];
  const int e  = blockIdx.z;
  const int p0 = blockIdx.y * 64;
  const int d0 = blockIdx.x * 64;
  const int tx = threadIdx.x & 63;
  const int ty = threadIdx.x >> 6;
  const float* src = w + ((size_t)e * D_DIM + d0) * P_DIM + p0;
#pragma unroll
  for (int i = 0; i < 16; ++i) {
    const int dr = i * 4 + ty;
    tile[dr][tx] = src[(size_t)dr * P_DIM + tx];
  }
  __syncthreads();
  unsigned short* dst = wt + ((size_t)e * P_DIM + p0) * D_DIM + d0;
#pragma unroll
  for (int i = 0; i < 16; ++i) {
    const int pr = i * 4 + ty;
    const int cc = tx ^ ((pr & 7) << 3);
    dst[(size_t)pr * D_DIM + cc] = f2bf(tile[tx][pr]);
  }
}

__global__ __launch_bounds__(256, 2) void moe_gemm_kernel(
    const float* __restrict__ x,
    const unsigned short* __restrict__ wt,
    const float* __restrict__ gate,
    const float* __restrict__ eb,
    float* __restrict__ out) {
  __shared__ unsigned short lA[128 * 64];
  __shared__ unsigned short lB[128 * 64];
  __shared__ float lG[128 * 8];
  __shared__ float lBias[E_NUM * 128];

  const int tid  = threadIdx.x;
  const int lane = tid & 63;
  const int wid  = tid >> 6;
  const int wr   = wid >> 1, wc = wid & 1;
  const int m0   = blockIdx.x * 128;
  const int n0   = blockIdx.y * 128;

  reinterpret_cast<float4*>(lG)[tid] =
      reinterpret_cast<const float4*>(gate + (size_t)m0 * E_NUM)[tid];
  {
    const int e = tid >> 5, cc = (tid & 31) * 4;
    *reinterpret_cast<float4*>(&lBias[e * 128 + cc]) =
        *reinterpret_cast<const float4*>(&eb[(size_t)e * P_DIM + n0 + cc]);
  }
  __syncthreads();

  const int rA   = tid >> 1;
  const int colA = (tid & 1) * 32;
  const float* xrow = x + (size_t)(m0 + rA) * D_DIM + colA;

  f32x4 acc[4][4];
#pragma unroll
  for (int i = 0; i < 4; ++i)
#pragma unroll
    for (int jj = 0; jj < 4; ++jj)
#pragma unroll
      for (int k = 0; k < 4; ++k) acc[i][jj][k] = 0.f;

  for (int e = 0; e < E_NUM; ++e) {
    const float gs = lG[rA * 8 + e];
    const unsigned short* wte = wt + ((size_t)e * P_DIM + n0) * D_DIM;
    for (int kt = 0; kt < 16; ++kt) {
      __syncthreads();
      const float4* apv = reinterpret_cast<const float4*>(xrow + kt * 64);
#pragma unroll
      for (int jj = 0; jj < 4; ++jj) {
        float4 p = apv[2 * jj], q = apv[2 * jj + 1];
        u16x8 v;
        v[0] = f2bf(p.x * gs); v[1] = f2bf(p.y * gs);
        v[2] = f2bf(p.z * gs); v[3] = f2bf(p.w * gs);
        v[4] = f2bf(q.x * gs); v[5] = f2bf(q.y * gs);
        v[6] = f2bf(q.z * gs); v[7] = f2bf(q.w * gs);
        const int idx = rA * 64 + ((colA + jj * 8) ^ ((rA & 7) << 3));
        *reinterpret_cast<u16x8*>(&lA[idx]) = v;
      }
#pragma unroll
      for (int i = 0; i < 4; ++i) {
        const int u  = tid + i * 256;
        const int rr = u >> 3;
        const int cc = u & 7;
        const unsigned short* src = wte + (size_t)rr * D_DIM + kt * 64 + cc * 8;
        __builtin_amdgcn_global_load_lds(
            (const __attribute__((address_space(1))) void*)src,
            (__attribute__((address_space(3))) void*)&lB[u * 8], 16, 0, 0);
      }
      __syncthreads();
#pragma unroll
      for (int kk = 0; kk < 2; ++kk) {
        const int e0 = kk * 32 + (lane >> 4) * 8;
        short8 a[4], b[4];
#pragma unroll
        for (int m = 0; m < 4; ++m) {
          const int r = wr * 64 + m * 16 + (lane & 15);
          a[m] = *reinterpret_cast<const short8*>(&lA[r * 64 + (e0 ^ ((r & 7) << 3))]);
        }
#pragma unroll
        for (int n = 0; n < 4; ++n) {
          const int r = wc * 64 + n * 16 + (lane & 15);
          b[n] = *reinterpret_cast<const short8*>(&lB[r * 64 + (e0 ^ ((r & 7) << 3))]);
        }
#pragma unroll
        for (int m = 0; m < 4; ++m)
#pragma unroll
          for (int n = 0; n < 4; ++n)
            acc[m][n] = __builtin_amdgcn_mfma_f32_16x16x32_bf16(a[m], b[n], acc[m][n], 0, 0, 0);
      }
    }
  }

#pragma unroll
  for (int m = 0; m < 4; ++m) {
#pragma unroll
    for (int n = 0; n < 4; ++n) {
      const int rbase = wr * 64 + m * 16 + ((lane >> 4) * 4);
      const int cl    = wc * 64 + n * 16 + (lane & 15);
#pragma unroll
      for (int reg = 0; reg < 4; ++reg) {
        const int r = rbase + reg;
        float bsum = 0.f;
#pragma unroll
        for (int e = 0; e < E_NUM; ++e) bsum += lG[r * 8 + e] * lBias[e * 128 + cl];
        out[(size_t)(m0 + r) * P_DIM + n0 + cl] = acc[m][n][reg] + bsum;
      }
    }
  }
}

// ============================ launch ============================

extern "C" void kernel_launch(void* const* d_in, const int* in_sizes, int n_in,
                              void* d_out, int out_size, void* d_ws, size_t ws_size,
                              hipStream_t stream) {
  const float* x  = (const float*)d_in[0];
  const float* gw = (const float*)d_in[1];
  const float* gb = (const float*)d_in[2];
  const float* ew = (const float*)d_in[3];
  const float* eb = (const float*)d_in[4];
  float* out = (float*)d_out;

  char* ws = (char*)d_ws;
  float* gate        = (float*)ws;                     // 256 KiB
  unsigned short* wt = (unsigned short*)(ws + 262144); // 16 MiB

  const size_t need_big = 262144ull + 16777216ull + 134217728ull;

  gate_kernel<<<M_TOT / 4, 256, 0, stream>>>(x, gw, gb, gate);

  if (ws_size >= need_big) {
    unsigned short* apb = (unsigned short*)(ws + 262144 + 16777216);  // 128 MiB
    hipMemsetAsync(d_out, 0, (size_t)out_size * sizeof(float), stream);
    wtrans2_kernel<<<dim3(D_DIM / 64, P_DIM / 64, E_NUM), 256, 0, stream>>>(ew, wt);
    aprep_kernel<<<M_TOT / 2, 256, 0, stream>>>(x, gate, apb);
    gemm_sk3_kernel<<<1024, 256, 0, stream>>>(apb, wt, gate, eb, out);
  } else {
    wtrans_kernel<<<dim3(D_DIM / 64, P_DIM / 64, E_NUM), 256, 0, stream>>>(ew, wt);
    moe_gemm_kernel<<<dim3(M_TOT / 128, P_DIM / 128), 256, 0, stream>>>(x, wt, gate, eb, out);
  }
}

// Round 10
// 190.079 us; speedup vs baseline: 1.0852x; 1.0852x over previous
//
#include <hip/hip_runtime.h>
#include <hip/hip_bf16.h>
#include <math.h>

#define M_TOT 8192
#define D_DIM 1024
#define E_NUM 8
#define P_DIM 1024
#define K_TOT (E_NUM * D_DIM)  // 8192

typedef __attribute__((ext_vector_type(8))) short short8;
typedef __attribute__((ext_vector_type(4))) float f32x4;
typedef __attribute__((ext_vector_type(8))) unsigned short u16x8;

// round-to-nearest-even f32 -> bf16 (finite inputs)
static __device__ __forceinline__ unsigned short f2bf(float f) {
  unsigned u = __builtin_bit_cast(unsigned, f);
  unsigned r = (u + 0x7fffu + ((u >> 16) & 1u)) >> 16;
  return (unsigned short)r;
}

// ---------------- gate: softmax(x @ gate_w + gate_b) -> [M, E] fp32 ----------------
__global__ __launch_bounds__(256) void gate_kernel(const float* __restrict__ x,
                                                   const float* __restrict__ gw,
                                                   const float* __restrict__ gb,
                                                   float* __restrict__ gate) {
  const int row  = blockIdx.x * 4 + (threadIdx.x >> 6);
  const int lane = threadIdx.x & 63;
  const float* xr = x + (size_t)row * D_DIM;
  float acc[E_NUM];
#pragma unroll
  for (int e = 0; e < E_NUM; ++e) acc[e] = 0.f;
#pragma unroll
  for (int it = 0; it < 16; ++it) {
    const int d = it * 64 + lane;
    const float xv = xr[d];
    const float4* g4 = reinterpret_cast<const float4*>(gw + (size_t)d * E_NUM);
    float4 a = g4[0], b = g4[1];
    acc[0] += xv * a.x; acc[1] += xv * a.y; acc[2] += xv * a.z; acc[3] += xv * a.w;
    acc[4] += xv * b.x; acc[5] += xv * b.y; acc[6] += xv * b.z; acc[7] += xv * b.w;
  }
#pragma unroll
  for (int off = 32; off >= 1; off >>= 1) {
#pragma unroll
    for (int e = 0; e < E_NUM; ++e) acc[e] += __shfl_xor(acc[e], off, 64);
  }
  if (lane == 0) {
    float v[E_NUM], mx = -1e30f;
#pragma unroll
    for (int e = 0; e < E_NUM; ++e) { v[e] = acc[e] + gb[e]; mx = fmaxf(mx, v[e]); }
    float s = 0.f;
#pragma unroll
    for (int e = 0; e < E_NUM; ++e) { v[e] = expf(v[e] - mx); s += v[e]; }
    const float inv = 1.f / s;
#pragma unroll
    for (int e = 0; e < E_NUM; ++e) gate[(size_t)row * E_NUM + e] = v[e] * inv;
  }
}

// ---------------- W [E][D][P] f32 -> wt [P][E*D] bf16, swizzle baked per 64-short K-block ----------------
__global__ __launch_bounds__(256) void wtrans2_kernel(const float* __restrict__ w,
                                                      unsigned short* __restrict__ wt) {
  __shared__ float tile[64][65];
  const int e  = blockIdx.z;
  const int p0 = blockIdx.y * 64;
  const int d0 = blockIdx.x * 64;
  const int tx = threadIdx.x & 63;
  const int ty = threadIdx.x >> 6;
  const float* src = w + ((size_t)e * D_DIM + d0) * P_DIM + p0;
#pragma unroll
  for (int i = 0; i < 16; ++i) {
    const int dr = i * 4 + ty;
    tile[dr][tx] = src[(size_t)dr * P_DIM + tx];
  }
  __syncthreads();
#pragma unroll
  for (int i = 0; i < 16; ++i) {
    const int pr = i * 4 + ty;
    const int c = tx ^ ((pr & 7) << 3);  // involution, 16B-chunk granular
    wt[(size_t)(p0 + pr) * K_TOT + e * D_DIM + d0 + c] = f2bf(tile[tx][pr]);
  }
}

// ---------------- xb[m][d] = bf16(x[m][d]), swizzle baked per 64-short K-block ----------------
__global__ __launch_bounds__(256) void xb_kernel(const float* __restrict__ x,
                                                 unsigned short* __restrict__ xb) {
  const int tid = threadIdx.x;
  const int m   = blockIdx.x * 2 + (tid >> 7);
  const int jd  = tid & 127;
  const float4* xp = reinterpret_cast<const float4*>(x + (size_t)m * D_DIM + jd * 8);
  const float4 p = xp[0], q = xp[1];
  const int cbase = (jd >> 3) * 8 + ((jd & 7) ^ (m & 7));
  u16x8 v;
  v[0] = f2bf(p.x); v[1] = f2bf(p.y); v[2] = f2bf(p.z); v[3] = f2bf(p.w);
  v[4] = f2bf(q.x); v[5] = f2bf(q.y); v[6] = f2bf(q.z); v[7] = f2bf(q.w);
  *reinterpret_cast<u16x8*>(&xb[(size_t)m * D_DIM + cbase * 8]) = v;
}

// ---- Horner-gated expert-loop GEMM: 128x128 tile, BK=64, 4 waves, single accumulator.
// Block = (mt, nt, kh); kh = expert half {0-3}/{4-7}. Between experts: acc *= g[e-1]/g[e].
// XCD map: xcd = nt -> per-XCD wt slice = 2MB, L2-resident; xb panels (256KB) L2-hot.
__global__ __launch_bounds__(256, 4) void gemm_ex_kernel(
    const unsigned short* __restrict__ xb,
    const unsigned short* __restrict__ wt,
    const float* __restrict__ gate,
    const float* __restrict__ eb,
    float* __restrict__ out) {
  __shared__ unsigned short lA[128 * 64];   // 16 KB
  __shared__ unsigned short lB[128 * 64];   // 16 KB
  __shared__ float lG[128 * 8];             // 4 KB  -> 36 KB total

  const int tid  = threadIdx.x;
  const int lane = tid & 63;
  const int wid  = tid >> 6;
  const int wr   = wid >> 1, wc = wid & 1;

  // 1024 blocks: xcd = bid&7 = nt; idx = bid>>3: kh = idx&1, mt = idx>>1.
  const int bid = blockIdx.x;
  const int nt  = bid & 7;
  const int idx = bid >> 3;
  const int kh  = idx & 1;
  const int mt  = idx >> 1;
  const int m0  = mt * 128, n0 = nt * 128;

  reinterpret_cast<float4*>(lG)[tid] =
      reinterpret_cast<const float4*>(gate + (size_t)m0 * E_NUM)[tid];

  f32x4 acc[4][4];
#pragma unroll
  for (int i = 0; i < 4; ++i)
#pragma unroll
    for (int j = 0; j < 4; ++j)
#pragma unroll
      for (int k = 0; k < 4; ++k) acc[i][j][k] = 0.f;

  const int r0 = tid >> 3;  // 0..31
  const int c8 = tid & 7;   // 16B chunk within 64-short block
  const unsigned short* pAb = xb + (size_t)(m0 + r0) * D_DIM + c8 * 8;
  const unsigned short* pBb = wt + (size_t)(n0 + r0) * K_TOT + c8 * 8;

  for (int e = 0; e < 4; ++e) {
    const int eg = kh * 4 + e;
    if (e > 0) {
      // Horner rescale: acc *= g[row][eg-1] / g[row][eg]  (softmax gates > 3e-4, safe)
#pragma unroll
      for (int m = 0; m < 4; ++m) {
#pragma unroll
        for (int reg = 0; reg < 4; ++reg) {
          const int r = wr * 64 + m * 16 + (lane >> 4) * 4 + reg;
          const float ratio = lG[r * 8 + (eg - 1)] / lG[r * 8 + eg];
#pragma unroll
          for (int n = 0; n < 4; ++n) acc[m][n][reg] *= ratio;
        }
      }
    }
    const unsigned short* pB = pBb + (size_t)eg * D_DIM;
    for (int kt = 0; kt < 16; ++kt) {
      __syncthreads();  // previous tile's LDS reads complete
#pragma unroll
      for (int i = 0; i < 4; ++i) {
        __builtin_amdgcn_global_load_lds(
            (const __attribute__((address_space(1))) void*)(pAb + (size_t)i * 32 * D_DIM + kt * 64),
            (__attribute__((address_space(3))) void*)&lA[(tid + i * 256) * 8], 16, 0, 0);
      }
#pragma unroll
      for (int i = 0; i < 4; ++i) {
        __builtin_amdgcn_global_load_lds(
            (const __attribute__((address_space(1))) void*)(pB + (size_t)i * 32 * K_TOT + kt * 64),
            (__attribute__((address_space(3))) void*)&lB[(tid + i * 256) * 8], 16, 0, 0);
      }
      __syncthreads();  // compiler drains vmcnt before barrier
#pragma unroll
      for (int kk = 0; kk < 2; ++kk) {
        const int e0 = kk * 32 + (lane >> 4) * 8;
        short8 a[4], b[4];
#pragma unroll
        for (int m = 0; m < 4; ++m) {
          const int r = wr * 64 + m * 16 + (lane & 15);
          a[m] = *reinterpret_cast<const short8*>(&lA[r * 64 + (e0 ^ ((r & 7) << 3))]);
        }
#pragma unroll
        for (int n = 0; n < 4; ++n) {
          const int r = wc * 64 + n * 16 + (lane & 15);
          b[n] = *reinterpret_cast<const short8*>(&lB[r * 64 + (e0 ^ ((r & 7) << 3))]);
        }
#pragma unroll
        for (int m = 0; m < 4; ++m)
#pragma unroll
          for (int n = 0; n < 4; ++n)
            acc[m][n] = __builtin_amdgcn_mfma_f32_16x16x32_bf16(a[m], b[n], acc[m][n], 0, 0, 0);
      }
    }
  }

  // ---- epilogue: final Horner scale by g[row][kh*4+3]; atomic accumulate; kh==0 adds bias ----
#pragma unroll
  for (int n = 0; n < 4; ++n) {
    const int cl = wc * 64 + n * 16 + (lane & 15);
    float lb[E_NUM];
    if (kh == 0) {
#pragma unroll
      for (int e = 0; e < E_NUM; ++e) lb[e] = eb[(size_t)e * P_DIM + n0 + cl];
    }
#pragma unroll
    for (int m = 0; m < 4; ++m) {
#pragma unroll
      for (int reg = 0; reg < 4; ++reg) {
        const int r  = wr * 64 + m * 16 + (lane >> 4) * 4 + reg;
        const float gl = lG[r * 8 + kh * 4 + 3];
        float v = acc[m][n][reg] * gl;
        if (kh == 0) {
          float bsum = 0.f;
#pragma unroll
          for (int e = 0; e < E_NUM; ++e) bsum += lG[r * 8 + e] * lb[e];
          v += bsum;
        }
        atomicAdd(&out[(size_t)(m0 + r) * P_DIM + n0 + cl], v);
      }
    }
  }
}

// ============================ FALLBACK PATH (round-2, passing) ============================

__global__ __launch_bounds__(256) void wtrans_kernel(const float* __restrict__ w,
                                                     unsigned short* __restrict__ wt) {
  __shared__ float tile[64][65];
  const int e  = blockIdx.z;
  const int p0 = blockIdx.y * 64;
  const int d0 = blockIdx.x * 64;
  const int tx = threadIdx.x & 63;
  const int ty = threadIdx.x >> 6;
  const float* src = w + ((size_t)e * D_DIM + d0) * P_DIM + p0;
#pragma unroll
  for (int i = 0; i < 16; ++i) {
    const int dr = i * 4 + ty;
    tile[dr][tx] = src[(size_t)dr * P_DIM + tx];
  }
  __syncthreads();
  unsigned short* dst = wt + ((size_t)e * P_DIM + p0) * D_DIM + d0;
#pragma unroll
  for (int i = 0; i < 16; ++i) {
    const int pr = i * 4 + ty;
    const int cc = tx ^ ((pr & 7) << 3);
    dst[(size_t)pr * D_DIM + cc] = f2bf(tile[tx][pr]);
  }
}

__global__ __launch_bounds__(256, 2) void moe_gemm_kernel(
    const float* __restrict__ x,
    const unsigned short* __restrict__ wt,
    const float* __restrict__ gate,
    const float* __restrict__ eb,
    float* __restrict__ out) {
  __shared__ unsigned short lA[128 * 64];
  __shared__ unsigned short lB[128 * 64];
  __shared__ float lG[128 * 8];
  __shared__ float lBias[E_NUM * 128];

  const int tid  = threadIdx.x;
  const int lane = tid & 63;
  const int wid  = tid >> 6;
  const int wr   = wid >> 1, wc = wid & 1;
  const int m0   = blockIdx.x * 128;
  const int n0   = blockIdx.y * 128;

  reinterpret_cast<float4*>(lG)[tid] =
      reinterpret_cast<const float4*>(gate + (size_t)m0 * E_NUM)[tid];
  {
    const int e = tid >> 5, cc = (tid & 31) * 4;
    *reinterpret_cast<float4*>(&lBias[e * 128 + cc]) =
        *reinterpret_cast<const float4*>(&eb[(size_t)e * P_DIM + n0 + cc]);
  }
  __syncthreads();

  const int rA   = tid >> 1;
  const int colA = (tid & 1) * 32;
  const float* xrow = x + (size_t)(m0 + rA) * D_DIM + colA;

  f32x4 acc[4][4];
#pragma unroll
  for (int i = 0; i < 4; ++i)
#pragma unroll
    for (int jj = 0; jj < 4; ++jj)
#pragma unroll
      for (int k = 0; k < 4; ++k) acc[i][jj][k] = 0.f;

  for (int e = 0; e < E_NUM; ++e) {
    const float gs = lG[rA * 8 + e];
    const unsigned short* wte = wt + ((size_t)e * P_DIM + n0) * D_DIM;
    for (int kt = 0; kt < 16; ++kt) {
      __syncthreads();
      const float4* apv = reinterpret_cast<const float4*>(xrow + kt * 64);
#pragma unroll
      for (int jj = 0; jj < 4; ++jj) {
        float4 p = apv[2 * jj], q = apv[2 * jj + 1];
        u16x8 v;
        v[0] = f2bf(p.x * gs); v[1] = f2bf(p.y * gs);
        v[2] = f2bf(p.z * gs); v[3] = f2bf(p.w * gs);
        v[4] = f2bf(q.x * gs); v[5] = f2bf(q.y * gs);
        v[6] = f2bf(q.z * gs); v[7] = f2bf(q.w * gs);
        const int idx = rA * 64 + ((colA + jj * 8) ^ ((rA & 7) << 3));
        *reinterpret_cast<u16x8*>(&lA[idx]) = v;
      }
#pragma unroll
      for (int i = 0; i < 4; ++i) {
        const int u  = tid + i * 256;
        const int rr = u >> 3;
        const int cc = u & 7;
        const unsigned short* src = wte + (size_t)rr * D_DIM + kt * 64 + cc * 8;
        __builtin_amdgcn_global_load_lds(
            (const __attribute__((address_space(1))) void*)src,
            (__attribute__((address_space(3))) void*)&lB[u * 8], 16, 0, 0);
      }
      __syncthreads();
#pragma unroll
      for (int kk = 0; kk < 2; ++kk) {
        const int e0 = kk * 32 + (lane >> 4) * 8;
        short8 a[4], b[4];
#pragma unroll
        for (int m = 0; m < 4; ++m) {
          const int r = wr * 64 + m * 16 + (lane & 15);
          a[m] = *reinterpret_cast<const short8*>(&lA[r * 64 + (e0 ^ ((r & 7) << 3))]);
        }
#pragma unroll
        for (int n = 0; n < 4; ++n) {
          const int r = wc * 64 + n * 16 + (lane & 15);
          b[n] = *reinterpret_cast<const short8*>(&lB[r * 64 + (e0 ^ ((r & 7) << 3))]);
        }
#pragma unroll
        for (int m = 0; m < 4; ++m)
#pragma unroll
          for (int n = 0; n < 4; ++n)
            acc[m][n] = __builtin_amdgcn_mfma_f32_16x16x32_bf16(a[m], b[n], acc[m][n], 0, 0, 0);
      }
    }
  }

#pragma unroll
  for (int m = 0; m < 4; ++m) {
#pragma unroll
    for (int n = 0; n < 4; ++n) {
      const int rbase = wr * 64 + m * 16 + ((lane >> 4) * 4);
      const int cl    = wc * 64 + n * 16 + (lane & 15);
#pragma unroll
      for (int reg = 0; reg < 4; ++reg) {
        const int r = rbase + reg;
        float bsum = 0.f;
#pragma unroll
        for (int e = 0; e < E_NUM; ++e) bsum += lG[r * 8 + e] * lBias[e * 128 + cl];
        out[(size_t)(m0 + r) * P_DIM + n0 + cl] = acc[m][n][reg] + bsum;
      }
    }
  }
}

// ============================ launch ============================

extern "C" void kernel_launch(void* const* d_in, const int* in_sizes, int n_in,
                              void* d_out, int out_size, void* d_ws, size_t ws_size,
                              hipStream_t stream) {
  const float* x  = (const float*)d_in[0];
  const float* gw = (const float*)d_in[1];
  const float* gb = (const float*)d_in[2];
  const float* ew = (const float*)d_in[3];
  const float* eb = (const float*)d_in[4];
  float* out = (float*)d_out;

  char* ws = (char*)d_ws;
  float* gate        = (float*)ws;                     // 256 KiB
  unsigned short* wt = (unsigned short*)(ws + 262144); // 16 MiB

  const size_t need_new = 262144ull + 16777216ull + 16777216ull;  // gate + wt + xb

  gate_kernel<<<M_TOT / 4, 256, 0, stream>>>(x, gw, gb, gate);

  if (ws_size >= need_new) {
    unsigned short* xbb = (unsigned short*)(ws + 262144 + 16777216);  // 16 MiB
    hipMemsetAsync(d_out, 0, (size_t)out_size * sizeof(float), stream);
    wtrans2_kernel<<<dim3(D_DIM / 64, P_DIM / 64, E_NUM), 256, 0, stream>>>(ew, wt);
    xb_kernel<<<M_TOT / 2, 256, 0, stream>>>(x, xbb);
    gemm_ex_kernel<<<1024, 256, 0, stream>>>(xbb, wt, gate, eb, out);
  } else {
    wtrans_kernel<<<dim3(D_DIM / 64, P_DIM / 64, E_NUM), 256, 0, stream>>>(ew, wt);
    moe_gemm_kernel<<<dim3(M_TOT / 128, P_DIM / 128), 256, 0, stream>>>(x, wt, gate, eb, out);
  }
}